// Round 4
// baseline (392.301 us; speedup 1.0000x reference)
//
#include <hip/hip_runtime.h>
#include <hip/hip_bf16.h>

typedef __attribute__((ext_vector_type(8))) short short8;
typedef __attribute__((ext_vector_type(4))) float floatx4;

__device__ __forceinline__ float sigm(float x) { return 1.0f / (1.0f + __expf(-x)); }

__device__ __forceinline__ unsigned short f2bf(float v) {
  union { __hip_bfloat16 h; unsigned short u; } cv;
  cv.h = __float2bfloat16(v);
  return cv.u;
}

// ---------------- prep: fold ia/im/bias into padded bf16 weights ----------------
// Combined channel c (0..170): c<18 -> det row c (scaled by im, bias im*(b + W.ia));
//                              c>=18 -> kpt row c-18 (bias bk). Rows 171..175 zero.
struct PrepArgs {
  const float *w, *b, *im, *ia, *wk, *bk;
  unsigned short* Wp;
  float* bias;
  int C;
};

__global__ void prep_kernel(PrepArgs A0, PrepArgs A1, PrepArgs A2) {
  PrepArgs A = (blockIdx.y == 0) ? A0 : (blockIdx.y == 1) ? A1 : A2;
  const int n = blockIdx.x;   // 0..175
  const int t = threadIdx.x;  // 0..63
  const int C = A.C;
  unsigned short* wrow = A.Wp + (size_t)n * C;
  if (n >= 171) {
    for (int k = t; k < C; k += 64) wrow[k] = 0;
    if (t == 0) A.bias[n] = 0.0f;
    return;
  }
  if (n < 18) {
    const float* src = A.w + (size_t)n * C;
    const float sc = A.im[n];
    float dot = 0.0f;
    for (int k = t; k < C; k += 64) {
      float v = src[k];
      dot += v * A.ia[k];
      wrow[k] = f2bf(v * sc);
    }
#pragma unroll
    for (int off = 32; off > 0; off >>= 1) dot += __shfl_down(dot, off);
    if (t == 0) A.bias[n] = sc * (A.b[n] + dot);
  } else {
    const float* src = A.wk + (size_t)(n - 18) * C;
    for (int k = t; k < C; k += 64) wrow[k] = f2bf(src[k]);
    if (t == 0) A.bias[n] = A.bk[n - 18];
  }
}

// ---------------- barrier-free, LDS-free K-loop GEMM (bf16 MFMA) + decode ----------
// Block = 64 m x 176 n, 4 waves; wave = 16 m x 176 n, fully self-paced.
// A: lane gathers ITS OWN fragment elements from global (addr = k*HW + m); the
//    gather pattern IS the MFMA A-layout — no LDS, no transpose, no barrier.
//    Double-buffered 2-iteration register prefetch hides ~900cyc HBM latency.
// B: fragments straight from L2-resident folded weights, 3-group register ring.
#define LDS_BYTES 23040  // epilogue tile only: 32 rows x 180 f32

template <int SC, int C, int HW, int W>
__device__ __forceinline__ void gemm_decode(const float* __restrict__ feat,
                                            const unsigned short* __restrict__ Wp,
                                            const float* __restrict__ bias,
                                            float* __restrict__ out, int tile, char* smem) {
  constexpr float STRD = (SC == 0) ? 8.0f : (SC == 1) ? 16.0f : 32.0f;
  constexpr int ZOFF = (SC == 0) ? 0 : (SC == 1) ? 19200 : 24000;
  constexpr int I = C / 64;

  const int t = threadIdx.x;
  const int lane = t & 63;
  const int wv = t >> 6;
  const int l15 = lane & 15;
  const int quad = lane >> 4;

  float* Elds = (float*)smem;  // [32][180] fp32 epilogue tile

  // per-lane A gather base: m = tile*64 + wv*16 + l15, k-base = quad*8
  const int mG = tile * 64 + wv * 16 + l15;
  const int bA = mG / HW;
  const int pA = mG - bA * HW;
  const float* gA = feat + ((size_t)bA * C + quad * 8) * (size_t)HW + pA;

  // B fragment base: n-row = l15, k-chunk = quad*8
  const unsigned short* bP = Wp + (size_t)l15 * C + quad * 8;

  floatx4 acc[11];
#pragma unroll
  for (int nj = 0; nj < 11; ++nj) acc[nj] = (floatx4){0.f, 0.f, 0.f, 0.f};

  auto loadA = [&](float (&dst)[16], int it) {
    const float* g = gA + (size_t)it * 64 * HW;
#pragma unroll
    for (int j = 0; j < 8; ++j) {
      dst[j] = g[(size_t)j * HW];           // k = quad*8 + j        (af0)
      dst[j + 8] = g[(size_t)(j + 32) * HW];  // k = quad*8 + j + 32 (af1)
    }
  };

  auto step = [&](float (&cur)[16], int it) {
    const unsigned short* bI = bP + (size_t)it * 64;
    // B ring: 3 groups in flight
    short8 breg[3][2];
#pragma unroll
    for (int j = 0; j < 3; ++j) {
      breg[j][0] = *(const short8*)(bI + (size_t)j * 16 * C);
      breg[j][1] = *(const short8*)(bI + (size_t)j * 16 * C + 32);
    }
    // A fragments from registers prefetched 2 iterations ago
    short8 af0, af1;
#pragma unroll
    for (int j = 0; j < 8; ++j) {
      af0[j] = (short)f2bf(cur[j]);
      af1[j] = (short)f2bf(cur[j + 8]);
    }
    // A prefetch for it+2 (same parity buffer, just consumed)
    if (it + 2 < I) loadA(cur, it + 2);
#pragma unroll
    for (int nj = 0; nj < 11; ++nj) {
      short8 b0 = breg[nj % 3][0];
      short8 b1 = breg[nj % 3][1];
      if (nj + 3 < 11) {
        breg[nj % 3][0] = *(const short8*)(bI + (size_t)(nj + 3) * 16 * C);
        breg[nj % 3][1] = *(const short8*)(bI + (size_t)(nj + 3) * 16 * C + 32);
      }
      acc[nj] = __builtin_amdgcn_mfma_f32_16x16x32_bf16(af0, b0, acc[nj], 0, 0, 0);
      acc[nj] = __builtin_amdgcn_mfma_f32_16x16x32_bf16(af1, b1, acc[nj], 0, 0, 0);
    }
  };

  float va[16], vb[16];
  loadA(va, 0);
  loadA(vb, 1);
  for (int it = 0; it < I; it += 2) {  // I is 4, 8, or 16 (always even)
    step(va, it);
    step(vb, it + 1);
  }

  // ---------------- epilogue: 2 chunks of 32 rows ----------------
  float bj[11];
#pragma unroll
  for (int nj = 0; nj < 11; ++nj) bj[nj] = bias[nj * 16 + l15];

#pragma unroll
  for (int c = 0; c < 2; ++c) {
    __syncthreads();
    if ((wv >> 1) == c) {
      const int rbase = (wv & 1) * 16 + quad * 4;
#pragma unroll
      for (int nj = 0; nj < 11; ++nj)
#pragma unroll
        for (int r = 0; r < 4; ++r)
          Elds[(rbase + r) * 180 + nj * 16 + l15] = acc[nj][r] + bj[nj];
    }
    __syncthreads();
    if (t < 192) {
      const int task = t >> 1, half = t & 1;
      const int row = task & 31, a = task >> 5;
      const int m = tile * 64 + c * 32 + row;
      const int bb = m / HW;
      const int p = m - bb * HW;
      const float fx = (float)(p % W);
      const float fy = (float)(p / W);
      float* L = Elds + row * 180 + a * 57;
      if (half == 0) {
        float aw, ah;
        if constexpr (SC == 0) {
          aw = (a == 0) ? 19.f : (a == 1) ? 44.f : 38.f;
          ah = (a == 0) ? 27.f : (a == 1) ? 40.f : 94.f;
        } else if constexpr (SC == 1) {
          aw = (a == 0) ? 96.f : (a == 1) ? 86.f : 180.f;
          ah = (a == 0) ? 68.f : (a == 1) ? 152.f : 137.f;
        } else {
          aw = (a == 0) ? 140.f : (a == 1) ? 303.f : 238.f;
          ah = (a == 0) ? 301.f : (a == 1) ? 264.f : 542.f;
        }
        float r0 = L[0], r1 = L[1], r2 = L[2], r3 = L[3], r4 = L[4], r5 = L[5];
        L[0] = (sigm(r0) * 2.f - 0.5f + fx) * STRD;
        L[1] = (sigm(r1) * 2.f - 0.5f + fy) * STRD;
        float tw = sigm(r2) * 2.f;
        L[2] = tw * tw * aw;
        float th = sigm(r3) * 2.f;
        L[3] = th * th * ah;
        L[4] = sigm(r4);
        L[5] = sigm(r5);
#pragma unroll
        for (int kp = 0; kp < 8; ++kp) {
          float kx = L[6 + 3 * kp], ky = L[7 + 3 * kp], kc = L[8 + 3 * kp];
          L[6 + 3 * kp] = (kx * 2.f - 0.5f + fx) * STRD;
          L[7 + 3 * kp] = (ky * 2.f - 0.5f + fy) * STRD;
          L[8 + 3 * kp] = sigm(kc);
        }
      } else {
#pragma unroll
        for (int kp = 8; kp < 17; ++kp) {
          float kx = L[6 + 3 * kp], ky = L[7 + 3 * kp], kc = L[8 + 3 * kp];
          L[6 + 3 * kp] = (kx * 2.f - 0.5f + fx) * STRD;
          L[7 + 3 * kp] = (ky * 2.f - 0.5f + fy) * STRD;
          L[8 + 3 * kp] = sigm(kc);
        }
      }
    }
    __syncthreads();
    for (int i = t; i < 96 * 57; i += 256) {
      int sr = i / 57;
      int j = i - sr * 57;
      int a = sr >> 5, row = sr & 31;
      int m = tile * 64 + c * 32 + row;
      int bb = m / HW;
      int p = m - bb * HW;
      out[((size_t)bb * 25200 + (size_t)(ZOFF + a * HW + p)) * 57 + j] =
          Elds[row * 180 + a * 57 + j];
    }
  }
}

__global__ __launch_bounds__(256, 4) void main_kernel(
    const float* __restrict__ f0, const float* __restrict__ f1, const float* __restrict__ f2,
    const unsigned short* __restrict__ Wp0, const unsigned short* __restrict__ Wp1,
    const unsigned short* __restrict__ Wp2, const float* __restrict__ b0,
    const float* __restrict__ b1, const float* __restrict__ b2, float* __restrict__ out) {
  __shared__ __align__(16) char smem[LDS_BYTES];
  const int bid = blockIdx.x;
  // longest blocks (scale 2, C=1024) first to amortize the tail
  if (bid < 100)
    gemm_decode<2, 1024, 400, 20>(f2, Wp2, b2, out, bid, smem);
  else if (bid < 500)
    gemm_decode<1, 512, 1600, 40>(f1, Wp1, b1, out, bid - 100, smem);
  else
    gemm_decode<0, 256, 6400, 80>(f0, Wp0, b0, out, bid - 500, smem);
}

extern "C" void kernel_launch(void* const* d_in, const int* in_sizes, int n_in, void* d_out,
                              int out_size, void* d_ws, size_t ws_size, hipStream_t stream) {
  const float *f[3], *ia[3], *w[3], *b[3], *im[3], *wk[3], *bk[3];
  for (int s = 0; s < 3; ++s) {
    f[s] = (const float*)d_in[7 * s + 0];
    ia[s] = (const float*)d_in[7 * s + 1];
    w[s] = (const float*)d_in[7 * s + 2];
    b[s] = (const float*)d_in[7 * s + 3];
    im[s] = (const float*)d_in[7 * s + 4];
    wk[s] = (const float*)d_in[7 * s + 5];
    bk[s] = (const float*)d_in[7 * s + 6];
  }
  // workspace: Wp0 98304B | Wp1 196608B | Wp2 393216B | 3x bias 192 f32
  char* ws = (char*)d_ws;
  unsigned short* Wp0 = (unsigned short*)(ws + 0);
  unsigned short* Wp1 = (unsigned short*)(ws + 98304);
  unsigned short* Wp2 = (unsigned short*)(ws + 294912);
  float* bias0 = (float*)(ws + 688128);
  float* bias1 = (float*)(ws + 688896);
  float* bias2 = (float*)(ws + 689664);

  PrepArgs A0 = {w[0], b[0], im[0], ia[0], wk[0], bk[0], Wp0, bias0, 256};
  PrepArgs A1 = {w[1], b[1], im[1], ia[1], wk[1], bk[1], Wp1, bias1, 512};
  PrepArgs A2 = {w[2], b[2], im[2], ia[2], wk[2], bk[2], Wp2, bias2, 1024};
  prep_kernel<<<dim3(176, 3), 64, 0, stream>>>(A0, A1, A2);

  main_kernel<<<2100, 256, 0, stream>>>(f[0], f[1], f[2], Wp0, Wp1, Wp2, bias0, bias1, bias2,
                                        (float*)d_out);
}